// Round 1
// baseline (520.814 us; speedup 1.0000x reference)
//
#include <hip/hip_runtime.h>
#include <hip/hip_bf16.h>

#define BB 2
#define TT 2048
#define DM 1024
#define NH 16
#define HD 64
#define BT (BB*TT)

typedef unsigned short u16;
typedef __attribute__((ext_vector_type(8))) short short8;
typedef __attribute__((ext_vector_type(4))) float f32x4;

__device__ __forceinline__ u16 f2b(float f){
  unsigned u = __builtin_bit_cast(unsigned, f);
  u += 0x7FFFu + ((u >> 16) & 1u);
  return (u16)(u >> 16);
}
__device__ __forceinline__ float b2f(u16 h){
  unsigned u = ((unsigned)h) << 16;
  return __builtin_bit_cast(float, u);
}

// ---------------- f32 -> bf16 conversion ----------------
__global__ __launch_bounds__(256) void cvt_kernel(const float* __restrict__ src,
                                                  u16* __restrict__ dst, int n4){
  int i = blockIdx.x*256 + threadIdx.x;
  if (i < n4){
    const float4 v = *(const float4*)(src + (size_t)i*4);
    ushort4 o;
    o.x = f2b(v.x); o.y = f2b(v.y); o.z = f2b(v.z); o.w = f2b(v.w);
    *(ushort4*)(dst + (size_t)i*4) = o;
  }
}

// ---------------- QKV projection: Y[m,n] = sum_k X[m,k]*W[n,k] ----------------
// wave computes 16 rows x 64 cols. grid.y = 3 selects (Wq,Qb) / (Wk,Kb) / (Wv,Vb).
__global__ __launch_bounds__(256) void gemm_qkv_kernel(const u16* __restrict__ Xb,
                                                       const u16* __restrict__ Wb,
                                                       u16* __restrict__ QKVb){
  const int proj = blockIdx.y;
  const u16* __restrict__ W = Wb + (size_t)proj*DM*DM;
  u16* __restrict__ Y = QKVb + (size_t)proj*BT*DM;
  const int lane = threadIdx.x & 63;
  const int wave = threadIdx.x >> 6;
  const int wg = blockIdx.x*4 + wave;        // 0..4095
  const int m0 = (wg >> 4) << 4;             // 256 m-tiles
  const int n0 = (wg & 15) << 6;             // 16 n-tiles of 64
  const int r = lane & 15, g = lane >> 4;

  f32x4 acc0={0,0,0,0}, acc1={0,0,0,0}, acc2={0,0,0,0}, acc3={0,0,0,0};
  const u16* A  = Xb + (size_t)(m0 + r)*DM;
  const u16* B0 = W + (size_t)(n0 + r)*DM;
  const u16* B1 = B0 + (size_t)16*DM;
  const u16* B2 = B0 + (size_t)32*DM;
  const u16* B3 = B0 + (size_t)48*DM;
  for (int k0 = 0; k0 < DM; k0 += 32){
    const int ko = k0 + g*8;
    const short8 a = *(const short8*)(A + ko);
    acc0 = __builtin_amdgcn_mfma_f32_16x16x32_bf16(a, *(const short8*)(B0 + ko), acc0, 0,0,0);
    acc1 = __builtin_amdgcn_mfma_f32_16x16x32_bf16(a, *(const short8*)(B1 + ko), acc1, 0,0,0);
    acc2 = __builtin_amdgcn_mfma_f32_16x16x32_bf16(a, *(const short8*)(B2 + ko), acc2, 0,0,0);
    acc3 = __builtin_amdgcn_mfma_f32_16x16x32_bf16(a, *(const short8*)(B3 + ko), acc3, 0,0,0);
  }
  #pragma unroll
  for (int i=0;i<4;i++){
    const size_t row = (size_t)(m0 + g*4 + i)*DM;
    Y[row + n0 + r]      = f2b(acc0[i]);
    Y[row + n0 + 16 + r] = f2b(acc1[i]);
    Y[row + n0 + 32 + r] = f2b(acc2[i]);
    Y[row + n0 + 48 + r] = f2b(acc3[i]);
  }
}

// ---------------- output projection: f32 out ----------------
__global__ __launch_bounds__(256) void gemm_out_kernel(const u16* __restrict__ Ob,
                                                       const u16* __restrict__ Wob,
                                                       float* __restrict__ out){
  const int lane = threadIdx.x & 63;
  const int wave = threadIdx.x >> 6;
  const int wg = blockIdx.x*4 + wave;
  const int m0 = (wg >> 4) << 4;
  const int n0 = (wg & 15) << 6;
  const int r = lane & 15, g = lane >> 4;

  f32x4 acc0={0,0,0,0}, acc1={0,0,0,0}, acc2={0,0,0,0}, acc3={0,0,0,0};
  const u16* A  = Ob + (size_t)(m0 + r)*DM;
  const u16* B0 = Wob + (size_t)(n0 + r)*DM;
  const u16* B1 = B0 + (size_t)16*DM;
  const u16* B2 = B0 + (size_t)32*DM;
  const u16* B3 = B0 + (size_t)48*DM;
  for (int k0 = 0; k0 < DM; k0 += 32){
    const int ko = k0 + g*8;
    const short8 a = *(const short8*)(A + ko);
    acc0 = __builtin_amdgcn_mfma_f32_16x16x32_bf16(a, *(const short8*)(B0 + ko), acc0, 0,0,0);
    acc1 = __builtin_amdgcn_mfma_f32_16x16x32_bf16(a, *(const short8*)(B1 + ko), acc1, 0,0,0);
    acc2 = __builtin_amdgcn_mfma_f32_16x16x32_bf16(a, *(const short8*)(B2 + ko), acc2, 0,0,0);
    acc3 = __builtin_amdgcn_mfma_f32_16x16x32_bf16(a, *(const short8*)(B3 + ko), acc3, 0,0,0);
  }
  #pragma unroll
  for (int i=0;i<4;i++){
    const size_t row = (size_t)(m0 + g*4 + i)*DM;
    out[row + n0 + r]      = acc0[i];
    out[row + n0 + 16 + r] = acc1[i];
    out[row + n0 + 32 + r] = acc2[i];
    out[row + n0 + 48 + r] = acc3[i];
  }
}

// ---------------- RoPE on Q,K (interleaved pairs, in place) ----------------
__global__ __launch_bounds__(256) void rope_kernel(u16* __restrict__ Qb, u16* __restrict__ Kb,
                                                   const int* __restrict__ pos){
  int i = blockIdx.x*256 + threadIdx.x;   // pair index
  if (i >= BT*DM/2) return;
  const int m = i >> 9;                   // row (b*T+t); 512 pairs/row
  const int e0 = (i & 511) << 1;
  const int fi = (e0 & 63) >> 1;          // freq index within head
  const float invf = expf(-(float)fi * 0.28782313662425575f);  // ln(10000)/32
  float s, c;
  sincosf((float)pos[m] * invf, &s, &c);
  const size_t base = (size_t)m*DM + e0;
  {
    const float x0 = b2f(Qb[base]), x1 = b2f(Qb[base+1]);
    Qb[base]   = f2b(c*x0 - s*x1);
    Qb[base+1] = f2b(c*x1 + s*x0);
  }
  {
    const float x0 = b2f(Kb[base]), x1 = b2f(Kb[base+1]);
    Kb[base]   = f2b(c*x0 - s*x1);
    Kb[base+1] = f2b(c*x1 + s*x0);
  }
}

// ---------------- causal flash attention ----------------
// one wave per 16-row q-tile of one (b,h). KV streamed in 32-col blocks.
__global__ __launch_bounds__(256) void attn_kernel(const u16* __restrict__ Qb,
                                                   const u16* __restrict__ Kb,
                                                   const u16* __restrict__ Vb,
                                                   u16* __restrict__ Ob){
  __shared__ u16 Plds[4][16][48];   // per-wave 16x32 P tile, padded stride 48
  const int lane = threadIdx.x & 63;
  const int wave = threadIdx.x >> 6;
  const int wg = blockIdx.x*4 + wave;   // 0..4095
  const int qt = wg & 127;
  const int bh = wg >> 7;               // 0..31
  const int bq = bh >> 4;
  const int h = bh & 15;
  const int q0 = qt << 4;
  const int r = lane & 15, g = lane >> 4;

  const u16* Qrow = Qb + (size_t)(bq*TT + q0 + r)*DM + h*HD;
  const short8 qf0 = *(const short8*)(Qrow + g*8);
  const short8 qf1 = *(const short8*)(Qrow + 32 + g*8);

  f32x4 o0={0,0,0,0}, o1={0,0,0,0}, o2={0,0,0,0}, o3={0,0,0,0};
  float mrow[4], lrow[4];
  #pragma unroll
  for (int i=0;i<4;i++){ mrow[i] = -3.0e38f; lrow[i] = 0.f; }

  for (int s0 = 0; s0 <= q0; s0 += 32){
    // ---- S = Q K^T for 16x32 block ----
    f32x4 sa0={0,0,0,0}, sa1={0,0,0,0};
    const u16* Krow0 = Kb + (size_t)(bq*TT + s0 + r)*DM + h*HD;
    const u16* Krow1 = Krow0 + (size_t)16*DM;
    sa0 = __builtin_amdgcn_mfma_f32_16x16x32_bf16(qf0, *(const short8*)(Krow0 + g*8),      sa0, 0,0,0);
    sa0 = __builtin_amdgcn_mfma_f32_16x16x32_bf16(qf1, *(const short8*)(Krow0 + 32 + g*8), sa0, 0,0,0);
    sa1 = __builtin_amdgcn_mfma_f32_16x16x32_bf16(qf0, *(const short8*)(Krow1 + g*8),      sa1, 0,0,0);
    sa1 = __builtin_amdgcn_mfma_f32_16x16x32_bf16(qf1, *(const short8*)(Krow1 + 32 + g*8), sa1, 0,0,0);

    // ---- scale + causal mask ----
    float sv0[4], sv1[4], pm[4];
    #pragma unroll
    for (int i=0;i<4;i++){
      const int q = q0 + g*4 + i;
      sv0[i] = (s0 + r      <= q) ? sa0[i]*0.125f : -3.0e38f;
      sv1[i] = (s0 + 16 + r <= q) ? sa1[i]*0.125f : -3.0e38f;
      pm[i] = fmaxf(sv0[i], sv1[i]);
    }
    // ---- row max across the 16 lanes holding this row's cols ----
    #pragma unroll
    for (int off=8; off>0; off>>=1){
      #pragma unroll
      for (int i=0;i<4;i++) pm[i] = fmaxf(pm[i], __shfl_xor(pm[i], off));
    }
    float corr[4], p0[4], p1[4], ps[4];
    #pragma unroll
    for (int i=0;i<4;i++){
      const float mn = fmaxf(mrow[i], pm[i]);
      corr[i] = __expf(mrow[i] - mn);
      mrow[i] = mn;
      p0[i] = __expf(sv0[i] - mn);
      p1[i] = __expf(sv1[i] - mn);
      ps[i] = p0[i] + p1[i];
    }
    #pragma unroll
    for (int off=8; off>0; off>>=1){
      #pragma unroll
      for (int i=0;i<4;i++) ps[i] += __shfl_xor(ps[i], off);
    }
    #pragma unroll
    for (int i=0;i<4;i++){
      lrow[i] = lrow[i]*corr[i] + ps[i];
      o0[i] *= corr[i]; o1[i] *= corr[i]; o2[i] *= corr[i]; o3[i] *= corr[i];
      Plds[wave][g*4+i][r]      = f2b(p0[i]);
      Plds[wave][g*4+i][16 + r] = f2b(p1[i]);
    }
    // ---- P (A-frag) from LDS; V (B-frag) scalar loads; O += P V ----
    const short8 pf = *(const short8*)(&Plds[wave][r][g*8]);
    const u16* Vbase = Vb + (size_t)(bq*TT + s0 + g*8)*DM + h*HD + r;
    short8 v0, v1, v2, v3;
    #pragma unroll
    for (int j=0;j<8;j++){
      const u16* vp = Vbase + (size_t)j*DM;
      v0[j] = (short)vp[0];
      v1[j] = (short)vp[16];
      v2[j] = (short)vp[32];
      v3[j] = (short)vp[48];
    }
    o0 = __builtin_amdgcn_mfma_f32_16x16x32_bf16(pf, v0, o0, 0,0,0);
    o1 = __builtin_amdgcn_mfma_f32_16x16x32_bf16(pf, v1, o1, 0,0,0);
    o2 = __builtin_amdgcn_mfma_f32_16x16x32_bf16(pf, v2, o2, 0,0,0);
    o3 = __builtin_amdgcn_mfma_f32_16x16x32_bf16(pf, v3, o3, 0,0,0);
  }
  float inv[4];
  #pragma unroll
  for (int i=0;i<4;i++) inv[i] = 1.0f / lrow[i];
  #pragma unroll
  for (int i=0;i<4;i++){
    const size_t row = (size_t)(bq*TT + q0 + g*4 + i)*DM + h*HD;
    Ob[row + r]      = f2b(o0[i]*inv[i]);
    Ob[row + 16 + r] = f2b(o1[i]*inv[i]);
    Ob[row + 32 + r] = f2b(o2[i]*inv[i]);
    Ob[row + 48 + r] = f2b(o3[i]*inv[i]);
  }
}

extern "C" void kernel_launch(void* const* d_in, const int* in_sizes, int n_in,
                              void* d_out, int out_size, void* d_ws, size_t ws_size,
                              hipStream_t stream) {
  const float* X  = (const float*)d_in[0];
  const int* pos  = (const int*)d_in[1];
  const float* Wq = (const float*)d_in[2];
  const float* Wk = (const float*)d_in[3];
  const float* Wv = (const float*)d_in[4];
  const float* Wo = (const float*)d_in[5];
  float* out = (float*)d_out;

  char* ws = (char*)d_ws;
  u16* Xb = (u16*)ws;                                    // 8 MB
  u16* Wb = (u16*)(ws + (size_t)8*1024*1024);            // 4 x 2 MB (q,k,v,o)
  u16* Qb = (u16*)(ws + (size_t)16*1024*1024);           // 8 MB
  u16* Kb = Qb + (size_t)BT*DM;                          // 8 MB
  u16* Vb = Kb + (size_t)BT*DM;                          // 8 MB
  u16* Ob = (u16*)(ws + (size_t)40*1024*1024);           // 8 MB

  const int DD = DM*DM;
  cvt_kernel<<<4096, 256, 0, stream>>>(X,  Xb, BT*DM/4);
  cvt_kernel<<<1024, 256, 0, stream>>>(Wq, Wb,          DD/4);
  cvt_kernel<<<1024, 256, 0, stream>>>(Wk, Wb + DD,     DD/4);
  cvt_kernel<<<1024, 256, 0, stream>>>(Wv, Wb + 2*DD,   DD/4);
  cvt_kernel<<<1024, 256, 0, stream>>>(Wo, Wb + 3*DD,   DD/4);

  dim3 gq(1024, 3);
  gemm_qkv_kernel<<<gq, 256, 0, stream>>>(Xb, Wb, Qb);
  rope_kernel<<<8192, 256, 0, stream>>>(Qb, Kb, pos);
  attn_kernel<<<1024, 256, 0, stream>>>(Qb, Kb, Vb, Ob);
  gemm_out_kernel<<<1024, 256, 0, stream>>>(Ob, Wb + 3*DD, out);
}

// Round 2
// 316.370 us; speedup vs baseline: 1.6462x; 1.6462x over previous
//
#include <hip/hip_runtime.h>
#include <hip/hip_bf16.h>

#define BB 2
#define TT 2048
#define DM 1024
#define NH 16
#define HD 64
#define BT (BB*TT)

typedef unsigned short u16;
typedef __attribute__((ext_vector_type(8))) short short8;
typedef __attribute__((ext_vector_type(4))) float f32x4;

__device__ __forceinline__ u16 f2b(float f){
  unsigned u = __builtin_bit_cast(unsigned, f);
  u += 0x7FFFu + ((u >> 16) & 1u);
  return (u16)(u >> 16);
}
__device__ __forceinline__ float b2f(u16 h){
  unsigned u = ((unsigned)h) << 16;
  return __builtin_bit_cast(float, u);
}

// ---------------- f32 -> bf16 conversion (X) ----------------
__global__ __launch_bounds__(256) void cvt_kernel(const float* __restrict__ src,
                                                  u16* __restrict__ dst, int n4){
  int i = blockIdx.x*256 + threadIdx.x;
  if (i < n4){
    const float4 v = *(const float4*)(src + (size_t)i*4);
    ushort4 o;
    o.x = f2b(v.x); o.y = f2b(v.y); o.z = f2b(v.z); o.w = f2b(v.w);
    *(ushort4*)(dst + (size_t)i*4) = o;
  }
}

// ---------------- fused weight conversion (4 x 1M elems) ----------------
__global__ __launch_bounds__(256) void cvt_w_kernel(const float* __restrict__ w0,
                                                    const float* __restrict__ w1,
                                                    const float* __restrict__ w2,
                                                    const float* __restrict__ w3,
                                                    u16* __restrict__ dst){
  const int seg = blockIdx.x >> 10;           // 1024 blocks per weight
  const int i = (blockIdx.x & 1023)*256 + threadIdx.x;   // quad index within weight
  const float* src = (seg==0)?w0:(seg==1)?w1:(seg==2)?w2:w3;
  const float4 v = *(const float4*)(src + (size_t)i*4);
  ushort4 o;
  o.x = f2b(v.x); o.y = f2b(v.y); o.z = f2b(v.z); o.w = f2b(v.w);
  *(ushort4*)(dst + (size_t)seg*DM*DM + (size_t)i*4) = o;
}

// ---------------- QKV projection: Y[m,n] = sum_k X[m,k]*W[n,k] ----------------
// wave computes 32 rows x 64 cols. grid.y = 3 selects (Wq,Qb)/(Wk,Kb)/(Wv,Vb).
__global__ __launch_bounds__(256) void gemm_qkv_kernel(const u16* __restrict__ Xb,
                                                       const u16* __restrict__ Wb,
                                                       u16* __restrict__ QKVb){
  const int proj = blockIdx.y;
  const u16* __restrict__ W = Wb + (size_t)proj*DM*DM;
  u16* __restrict__ Y = QKVb + (size_t)proj*BT*DM;
  const int lane = threadIdx.x & 63;
  const int wave = threadIdx.x >> 6;
  const int wg = blockIdx.x*4 + wave;        // 0..2047
  const int m0 = (wg >> 4) << 5;             // 128 m-tiles of 32
  const int n0 = (wg & 15) << 6;             // 16 n-tiles of 64
  const int r = lane & 15, g = lane >> 4;

  f32x4 aA0={0,0,0,0}, aA1={0,0,0,0}, aA2={0,0,0,0}, aA3={0,0,0,0};
  f32x4 aB0={0,0,0,0}, aB1={0,0,0,0}, aB2={0,0,0,0}, aB3={0,0,0,0};
  const u16* A0 = Xb + (size_t)(m0 + r)*DM;
  const u16* A1 = A0 + (size_t)16*DM;
  const u16* B0 = W + (size_t)(n0 + r)*DM;
  const u16* B1 = B0 + (size_t)16*DM;
  const u16* B2 = B0 + (size_t)32*DM;
  const u16* B3 = B0 + (size_t)48*DM;
  for (int k0 = 0; k0 < DM; k0 += 32){
    const int ko = k0 + g*8;
    const short8 a0 = *(const short8*)(A0 + ko);
    const short8 a1 = *(const short8*)(A1 + ko);
    const short8 b0 = *(const short8*)(B0 + ko);
    const short8 b1 = *(const short8*)(B1 + ko);
    const short8 b2 = *(const short8*)(B2 + ko);
    const short8 b3 = *(const short8*)(B3 + ko);
    aA0 = __builtin_amdgcn_mfma_f32_16x16x32_bf16(a0, b0, aA0, 0,0,0);
    aA1 = __builtin_amdgcn_mfma_f32_16x16x32_bf16(a0, b1, aA1, 0,0,0);
    aA2 = __builtin_amdgcn_mfma_f32_16x16x32_bf16(a0, b2, aA2, 0,0,0);
    aA3 = __builtin_amdgcn_mfma_f32_16x16x32_bf16(a0, b3, aA3, 0,0,0);
    aB0 = __builtin_amdgcn_mfma_f32_16x16x32_bf16(a1, b0, aB0, 0,0,0);
    aB1 = __builtin_amdgcn_mfma_f32_16x16x32_bf16(a1, b1, aB1, 0,0,0);
    aB2 = __builtin_amdgcn_mfma_f32_16x16x32_bf16(a1, b2, aB2, 0,0,0);
    aB3 = __builtin_amdgcn_mfma_f32_16x16x32_bf16(a1, b3, aB3, 0,0,0);
  }
  #pragma unroll
  for (int i=0;i<4;i++){
    size_t row = (size_t)(m0 + g*4 + i)*DM;
    Y[row + n0 + r]      = f2b(aA0[i]);
    Y[row + n0 + 16 + r] = f2b(aA1[i]);
    Y[row + n0 + 32 + r] = f2b(aA2[i]);
    Y[row + n0 + 48 + r] = f2b(aA3[i]);
    row += (size_t)16*DM;
    Y[row + n0 + r]      = f2b(aB0[i]);
    Y[row + n0 + 16 + r] = f2b(aB1[i]);
    Y[row + n0 + 32 + r] = f2b(aB2[i]);
    Y[row + n0 + 48 + r] = f2b(aB3[i]);
  }
}

// ---------------- output projection: f32 out ----------------
__global__ __launch_bounds__(256) void gemm_out_kernel(const u16* __restrict__ Ob,
                                                       const u16* __restrict__ Wob,
                                                       float* __restrict__ out){
  const int lane = threadIdx.x & 63;
  const int wave = threadIdx.x >> 6;
  const int wg = blockIdx.x*4 + wave;        // 0..2047
  const int m0 = (wg >> 4) << 5;
  const int n0 = (wg & 15) << 6;
  const int r = lane & 15, g = lane >> 4;

  f32x4 aA0={0,0,0,0}, aA1={0,0,0,0}, aA2={0,0,0,0}, aA3={0,0,0,0};
  f32x4 aB0={0,0,0,0}, aB1={0,0,0,0}, aB2={0,0,0,0}, aB3={0,0,0,0};
  const u16* A0 = Ob + (size_t)(m0 + r)*DM;
  const u16* A1 = A0 + (size_t)16*DM;
  const u16* B0 = Wob + (size_t)(n0 + r)*DM;
  const u16* B1 = B0 + (size_t)16*DM;
  const u16* B2 = B0 + (size_t)32*DM;
  const u16* B3 = B0 + (size_t)48*DM;
  for (int k0 = 0; k0 < DM; k0 += 32){
    const int ko = k0 + g*8;
    const short8 a0 = *(const short8*)(A0 + ko);
    const short8 a1 = *(const short8*)(A1 + ko);
    const short8 b0 = *(const short8*)(B0 + ko);
    const short8 b1 = *(const short8*)(B1 + ko);
    const short8 b2 = *(const short8*)(B2 + ko);
    const short8 b3 = *(const short8*)(B3 + ko);
    aA0 = __builtin_amdgcn_mfma_f32_16x16x32_bf16(a0, b0, aA0, 0,0,0);
    aA1 = __builtin_amdgcn_mfma_f32_16x16x32_bf16(a0, b1, aA1, 0,0,0);
    aA2 = __builtin_amdgcn_mfma_f32_16x16x32_bf16(a0, b2, aA2, 0,0,0);
    aA3 = __builtin_amdgcn_mfma_f32_16x16x32_bf16(a0, b3, aA3, 0,0,0);
    aB0 = __builtin_amdgcn_mfma_f32_16x16x32_bf16(a1, b0, aB0, 0,0,0);
    aB1 = __builtin_amdgcn_mfma_f32_16x16x32_bf16(a1, b1, aB1, 0,0,0);
    aB2 = __builtin_amdgcn_mfma_f32_16x16x32_bf16(a1, b2, aB2, 0,0,0);
    aB3 = __builtin_amdgcn_mfma_f32_16x16x32_bf16(a1, b3, aB3, 0,0,0);
  }
  #pragma unroll
  for (int i=0;i<4;i++){
    size_t row = (size_t)(m0 + g*4 + i)*DM;
    out[row + n0 + r]      = aA0[i];
    out[row + n0 + 16 + r] = aA1[i];
    out[row + n0 + 32 + r] = aA2[i];
    out[row + n0 + 48 + r] = aA3[i];
    row += (size_t)16*DM;
    out[row + n0 + r]      = aB0[i];
    out[row + n0 + 16 + r] = aB1[i];
    out[row + n0 + 32 + r] = aB2[i];
    out[row + n0 + 48 + r] = aB3[i];
  }
}

// ---------------- RoPE on Q,K: one sincos per (row, freq), 16 heads ----------------
__global__ __launch_bounds__(256) void rope_kernel(u16* __restrict__ Qb, u16* __restrict__ Kb,
                                                   const int* __restrict__ pos){
  const int t = blockIdx.x*256 + threadIdx.x;   // 0..131071
  const int m = t >> 5;                         // row 0..4095
  const int fi = t & 31;                        // freq index
  const float invf = __expf(-(float)fi * 0.28782313662425575f);  // ln(10000)/32
  float s, c;
  sincosf((float)pos[m] * invf, &s, &c);
  const size_t base = (size_t)m*DM + fi*2;
  #pragma unroll
  for (int h=0; h<NH; h++){
    const size_t a = base + h*HD;
    {
      const float x0 = b2f(Qb[a]), x1 = b2f(Qb[a+1]);
      Qb[a]   = f2b(c*x0 - s*x1);
      Qb[a+1] = f2b(c*x1 + s*x0);
    }
    {
      const float x0 = b2f(Kb[a]), x1 = b2f(Kb[a+1]);
      Kb[a]   = f2b(c*x0 - s*x1);
      Kb[a+1] = f2b(c*x1 + s*x0);
    }
  }
}

// ---------------- V transpose: Vb[b*T+s][h*64+d] -> Vt[bh][d][s] ----------------
__global__ __launch_bounds__(256) void transpose_v_kernel(const u16* __restrict__ Vb,
                                                          u16* __restrict__ Vt){
  __shared__ u16 tile[64][72];   // row stride 144B (16B-aligned)
  const int bh = blockIdx.x >> 5;         // 0..31
  const int sc = blockIdx.x & 31;         // s-chunk 0..31
  const int bq = bh >> 4, h = bh & 15;
  const int s0 = sc*64;
  {
    const int row = threadIdx.x >> 3;        // 0..31
    const int c8 = (threadIdx.x & 7)*8;
    #pragma unroll
    for (int rr = 0; rr < 64; rr += 32){
      const short8 v = *(const short8*)(Vb + (size_t)(bq*TT + s0 + row + rr)*DM + h*HD + c8);
      *(short8*)(&tile[row+rr][c8]) = v;
    }
  }
  __syncthreads();
  {
    const int d = threadIdx.x >> 3;          // 0..31
    const int s8 = (threadIdx.x & 7)*8;
    #pragma unroll
    for (int dd = 0; dd < 64; dd += 32){
      short8 ov;
      #pragma unroll
      for (int j=0;j<8;j++) ov[j] = (short)tile[s8+j][d+dd];
      *(short8*)(Vt + ((size_t)bh*HD + d + dd)*TT + s0 + s8) = ov;
    }
  }
}

// ---------------- causal flash attention (paired q-tiles) ----------------
__device__ __forceinline__ void proc_tile(
    const short8 qf0, const short8 qf1,
    const short8 k00, const short8 k01, const short8 k10, const short8 k11,
    const short8 v0, const short8 v1, const short8 v2, const short8 v3,
    f32x4& o0, f32x4& o1, f32x4& o2, f32x4& o3,
    float (&mrow)[4], float (&lrow)[4],
    const int q0, const int s0, const int r, const int g,
    u16 (*pbuf)[40]){
  f32x4 sa0={0,0,0,0}, sa1={0,0,0,0};
  sa0 = __builtin_amdgcn_mfma_f32_16x16x32_bf16(qf0, k00, sa0, 0,0,0);
  sa0 = __builtin_amdgcn_mfma_f32_16x16x32_bf16(qf1, k01, sa0, 0,0,0);
  sa1 = __builtin_amdgcn_mfma_f32_16x16x32_bf16(qf0, k10, sa1, 0,0,0);
  sa1 = __builtin_amdgcn_mfma_f32_16x16x32_bf16(qf1, k11, sa1, 0,0,0);

  float sv0[4], sv1[4], pm[4];
  #pragma unroll
  for (int i=0;i<4;i++){
    const int q = q0 + g*4 + i;
    sv0[i] = (s0 + r      <= q) ? sa0[i]*0.125f : -3.0e38f;
    sv1[i] = (s0 + 16 + r <= q) ? sa1[i]*0.125f : -3.0e38f;
    pm[i] = fmaxf(sv0[i], sv1[i]);
  }
  #pragma unroll
  for (int off=8; off>0; off>>=1){
    #pragma unroll
    for (int i=0;i<4;i++) pm[i] = fmaxf(pm[i], __shfl_xor(pm[i], off));
  }
  float corr[4], p0[4], p1[4], ps[4];
  #pragma unroll
  for (int i=0;i<4;i++){
    const float mn = fmaxf(mrow[i], pm[i]);
    corr[i] = __expf(mrow[i] - mn);
    mrow[i] = mn;
    p0[i] = __expf(sv0[i] - mn);
    p1[i] = __expf(sv1[i] - mn);
    ps[i] = p0[i] + p1[i];
  }
  #pragma unroll
  for (int off=8; off>0; off>>=1){
    #pragma unroll
    for (int i=0;i<4;i++) ps[i] += __shfl_xor(ps[i], off);
  }
  #pragma unroll
  for (int i=0;i<4;i++){
    lrow[i] = lrow[i]*corr[i] + ps[i];
    o0[i] *= corr[i]; o1[i] *= corr[i]; o2[i] *= corr[i]; o3[i] *= corr[i];
    pbuf[g*4+i][r]      = f2b(p0[i]);
    pbuf[g*4+i][16 + r] = f2b(p1[i]);
  }
  const short8 pf = *(const short8*)(&pbuf[r][g*8]);
  o0 = __builtin_amdgcn_mfma_f32_16x16x32_bf16(pf, v0, o0, 0,0,0);
  o1 = __builtin_amdgcn_mfma_f32_16x16x32_bf16(pf, v1, o1, 0,0,0);
  o2 = __builtin_amdgcn_mfma_f32_16x16x32_bf16(pf, v2, o2, 0,0,0);
  o3 = __builtin_amdgcn_mfma_f32_16x16x32_bf16(pf, v3, o3, 0,0,0);
}

__global__ __launch_bounds__(256) void attn_kernel(const u16* __restrict__ Qb,
                                                   const u16* __restrict__ Kb,
                                                   const u16* __restrict__ Vt,
                                                   u16* __restrict__ Ob){
  __shared__ u16 Plds[4][2][16][40];
  const int lane = threadIdx.x & 63;
  const int wave = threadIdx.x >> 6;
  const int wg = blockIdx.x*4 + wave;   // 0..2047
  const int qt = wg & 63;               // pair id
  const int bh = wg >> 6;               // 0..31
  const int bq = bh >> 4;
  const int h = bh & 15;
  const int qlo = qt << 4;
  const int qhi = (127 - qt) << 4;
  const int r = lane & 15, g = lane >> 4;

  const u16* QrowL = Qb + (size_t)(bq*TT + qlo + r)*DM + h*HD;
  const u16* QrowH = Qb + (size_t)(bq*TT + qhi + r)*DM + h*HD;
  const short8 qL0 = *(const short8*)(QrowL + g*8);
  const short8 qL1 = *(const short8*)(QrowL + 32 + g*8);
  const short8 qH0 = *(const short8*)(QrowH + g*8);
  const short8 qH1 = *(const short8*)(QrowH + 32 + g*8);

  f32x4 oL0={0,0,0,0}, oL1={0,0,0,0}, oL2={0,0,0,0}, oL3={0,0,0,0};
  f32x4 oH0={0,0,0,0}, oH1={0,0,0,0}, oH2={0,0,0,0}, oH3={0,0,0,0};
  float mL[4], lL[4], mH[4], lH[4];
  #pragma unroll
  for (int i=0;i<4;i++){ mL[i]=-3.0e38f; lL[i]=0.f; mH[i]=-3.0e38f; lH[i]=0.f; }

  const int nbL = ((qlo + 15) >> 5) + 1;
  const int nbH = ((qhi + 15) >> 5) + 1;
  const u16* Kbase = Kb + (size_t)(bq*TT)*DM + h*HD;
  const u16* Vtb = Vt + (size_t)bh*HD*TT;

  for (int ib = 0; ib < nbH; ib++){
    const int s0 = ib << 5;
    const u16* Kr0 = Kbase + (size_t)(s0 + r)*DM;
    const u16* Kr1 = Kr0 + (size_t)16*DM;
    const short8 k00 = *(const short8*)(Kr0 + g*8);
    const short8 k01 = *(const short8*)(Kr0 + 32 + g*8);
    const short8 k10 = *(const short8*)(Kr1 + g*8);
    const short8 k11 = *(const short8*)(Kr1 + 32 + g*8);
    const u16* Vr = Vtb + (size_t)r*TT + s0 + g*8;
    const short8 v0 = *(const short8*)(Vr);
    const short8 v1 = *(const short8*)(Vr + (size_t)16*TT);
    const short8 v2 = *(const short8*)(Vr + (size_t)32*TT);
    const short8 v3 = *(const short8*)(Vr + (size_t)48*TT);

    proc_tile(qH0,qH1,k00,k01,k10,k11,v0,v1,v2,v3,
              oH0,oH1,oH2,oH3,mH,lH,qhi,s0,r,g,Plds[wave][0]);
    if (ib < nbL){
      proc_tile(qL0,qL1,k00,k01,k10,k11,v0,v1,v2,v3,
                oL0,oL1,oL2,oL3,mL,lL,qlo,s0,r,g,Plds[wave][1]);
    }
  }
  float invL[4], invH[4];
  #pragma unroll
  for (int i=0;i<4;i++){ invL[i] = 1.0f/lL[i]; invH[i] = 1.0f/lH[i]; }
  #pragma unroll
  for (int i=0;i<4;i++){
    const size_t rowL = (size_t)(bq*TT + qlo + g*4 + i)*DM + h*HD;
    Ob[rowL + r]      = f2b(oL0[i]*invL[i]);
    Ob[rowL + 16 + r] = f2b(oL1[i]*invL[i]);
    Ob[rowL + 32 + r] = f2b(oL2[i]*invL[i]);
    Ob[rowL + 48 + r] = f2b(oL3[i]*invL[i]);
    const size_t rowH = (size_t)(bq*TT + qhi + g*4 + i)*DM + h*HD;
    Ob[rowH + r]      = f2b(oH0[i]*invH[i]);
    Ob[rowH + 16 + r] = f2b(oH1[i]*invH[i]);
    Ob[rowH + 32 + r] = f2b(oH2[i]*invH[i]);
    Ob[rowH + 48 + r] = f2b(oH3[i]*invH[i]);
  }
}

extern "C" void kernel_launch(void* const* d_in, const int* in_sizes, int n_in,
                              void* d_out, int out_size, void* d_ws, size_t ws_size,
                              hipStream_t stream) {
  const float* X  = (const float*)d_in[0];
  const int* pos  = (const int*)d_in[1];
  const float* Wq = (const float*)d_in[2];
  const float* Wk = (const float*)d_in[3];
  const float* Wv = (const float*)d_in[4];
  const float* Wo = (const float*)d_in[5];
  float* out = (float*)d_out;

  char* ws = (char*)d_ws;
  u16* Xb = (u16*)ws;                                    // 8 MB (reused as Vt later)
  u16* Vt = (u16*)ws;                                    // aliases Xb (dead after QKV gemm)
  u16* Wb = (u16*)(ws + (size_t)8*1024*1024);            // 4 x 2 MB (q,k,v,o)
  u16* Qb = (u16*)(ws + (size_t)16*1024*1024);           // 8 MB
  u16* Kb = Qb + (size_t)BT*DM;                          // 8 MB
  u16* Vb = Kb + (size_t)BT*DM;                          // 8 MB
  u16* Ob = (u16*)(ws + (size_t)40*1024*1024);           // 8 MB

  cvt_kernel<<<4096, 256, 0, stream>>>(X, Xb, BT*DM/4);
  cvt_w_kernel<<<4096, 256, 0, stream>>>(Wq, Wk, Wv, Wo, Wb);

  dim3 gq(512, 3);
  gemm_qkv_kernel<<<gq, 256, 0, stream>>>(Xb, Wb, Qb);
  rope_kernel<<<512, 256, 0, stream>>>(Qb, Kb, pos);
  transpose_v_kernel<<<1024, 256, 0, stream>>>(Vb, Vt);
  attn_kernel<<<512, 256, 0, stream>>>(Qb, Kb, Vt, Ob);
  gemm_out_kernel<<<512, 256, 0, stream>>>(Ob, Wb + 3*DM*DM, out);
}

// Round 3
// 198.351 us; speedup vs baseline: 2.6257x; 1.5950x over previous
//
#include <hip/hip_runtime.h>
#include <hip/hip_bf16.h>

#define BB 2
#define TT 2048
#define DM 1024
#define NH 16
#define HD 64
#define BT (BB*TT)

typedef unsigned short u16;
typedef __attribute__((ext_vector_type(8))) short short8;
typedef __attribute__((ext_vector_type(4))) float f32x4;

__device__ __forceinline__ u16 f2b(float f){
  unsigned u = __builtin_bit_cast(unsigned, f);
  u += 0x7FFFu + ((u >> 16) & 1u);
  return (u16)(u >> 16);
}
__device__ __forceinline__ float b2f(u16 h){
  unsigned u = ((unsigned)h) << 16;
  return __builtin_bit_cast(float, u);
}

__device__ __forceinline__ void gll16(const u16* g, u16* l){
  __builtin_amdgcn_global_load_lds((const __attribute__((address_space(1))) void*)g,
                                   (__attribute__((address_space(3))) void*)l, 16, 0, 0);
}

// ---------------- f32 -> bf16 conversion (X) ----------------
__global__ __launch_bounds__(256) void cvt_kernel(const float* __restrict__ src,
                                                  u16* __restrict__ dst, int n4){
  int i = blockIdx.x*256 + threadIdx.x;
  if (i < n4){
    const float4 v = *(const float4*)(src + (size_t)i*4);
    ushort4 o;
    o.x = f2b(v.x); o.y = f2b(v.y); o.z = f2b(v.z); o.w = f2b(v.w);
    *(ushort4*)(dst + (size_t)i*4) = o;
  }
}

// ---------------- fused weight conversion (4 x 1M elems) ----------------
__global__ __launch_bounds__(256) void cvt_w_kernel(const float* __restrict__ w0,
                                                    const float* __restrict__ w1,
                                                    const float* __restrict__ w2,
                                                    const float* __restrict__ w3,
                                                    u16* __restrict__ dst){
  const int seg = blockIdx.x >> 10;
  const int i = (blockIdx.x & 1023)*256 + threadIdx.x;
  const float* src = (seg==0)?w0:(seg==1)?w1:(seg==2)?w2:w3;
  const float4 v = *(const float4*)(src + (size_t)i*4);
  ushort4 o;
  o.x = f2b(v.x); o.y = f2b(v.y); o.z = f2b(v.z); o.w = f2b(v.w);
  *(ushort4*)(dst + (size_t)seg*DM*DM + (size_t)i*4) = o;
}

// ---------------- 128x128-tile LDS-staged GEMM: Y[m,n] = sum_k A[m,k] W[n,k] ----
// MODE 0: Ybf split into 3 proj buffers by n>>10 (QKV). MODE 1: f32 out, N=1024.
// LDS swizzle: logical k-slot g lives at phys slot g ^ ((row>>1)&3)  (2-way max).
#define FRAG(buf, row) (*(const short8*)((buf) + (size_t)(row)*32 + ((g ^ (((row)>>1)&3))*8)))

template<int MODE>
__global__ __launch_bounds__(256) void gemm128(const u16* __restrict__ A,
                                               const u16* __restrict__ W,
                                               u16* __restrict__ Ybf,
                                               float* __restrict__ Yf){
  __shared__ u16 sA0[4096], sB0[4096], sA1[4096], sB1[4096];
  const int tid = threadIdx.x;
  const int lane = tid & 63;
  const int wave = tid >> 6;
  const int r = lane & 15, g = lane >> 4;
  const int wr = wave >> 1, wc = wave & 1;
  const int m0 = blockIdx.y << 7;
  const int nn0 = blockIdx.x << 7;

  // staging map: thread tid covers lds elems [tid*8, tid*8+8) and +2048;
  // source column pre-swizzled so swizzled FRAG reads see logical layout.
  const int srow = tid >> 2;                                  // 0..63
  const int lcol = (((tid & 3) ^ ((srow >> 1) & 3))) * 8;     // same for row+64

  const u16* gA0 = A + (size_t)(m0 + srow)*DM + lcol;
  const u16* gA1 = gA0 + (size_t)64*DM;
  const u16* gB0 = W + (size_t)(nn0 + srow)*DM + lcol;
  const u16* gB1 = gB0 + (size_t)64*DM;

  f32x4 acc[4][4];
  #pragma unroll
  for (int i=0;i<4;i++)
    #pragma unroll
    for (int j=0;j<4;j++) acc[i][j] = (f32x4){0.f,0.f,0.f,0.f};

#define STAGE(SA, SB, koff) { \
    gll16(gA0 + (koff), SA + (size_t)tid*8); \
    gll16(gA1 + (koff), SA + 2048 + (size_t)tid*8); \
    gll16(gB0 + (koff), SB + (size_t)tid*8); \
    gll16(gB1 + (koff), SB + 2048 + (size_t)tid*8); }

#define COMPUTE(SA, SB) { \
    short8 af[4], bf[4]; \
    _Pragma("unroll") \
    for (int f=0; f<4; f++){ \
      af[f] = FRAG(SA, wr*64 + f*16 + r); \
      bf[f] = FRAG(SB, wc*64 + f*16 + r); \
    } \
    _Pragma("unroll") \
    for (int fr=0; fr<4; fr++) \
      _Pragma("unroll") \
      for (int fn=0; fn<4; fn++) \
        acc[fr][fn] = __builtin_amdgcn_mfma_f32_16x16x32_bf16(af[fr], bf[fn], acc[fr][fn], 0,0,0); }

  STAGE(sA0, sB0, 0);
  __syncthreads();

  for (int t = 0; t < 32; t += 2){
    if (t + 1 < 32) STAGE(sA1, sB1, (t+1)*32);
    COMPUTE(sA0, sB0);
    __syncthreads();
    if (t + 2 < 32) STAGE(sA0, sB0, (t+2)*32);
    COMPUTE(sA1, sB1);
    __syncthreads();
  }

  #pragma unroll
  for (int fr=0; fr<4; fr++){
    #pragma unroll
    for (int i=0;i<4;i++){
      const int m = m0 + wr*64 + fr*16 + g*4 + i;
      #pragma unroll
      for (int fn=0; fn<4; fn++){
        const int nn = nn0 + wc*64 + fn*16 + r;
        if (MODE == 0){
          Ybf[(size_t)(nn >> 10)*BT*DM + (size_t)m*DM + (nn & 1023)] = f2b(acc[fr][fn][i]);
        } else {
          Yf[(size_t)m*DM + nn] = acc[fr][fn][i];
        }
      }
    }
  }
#undef STAGE
#undef COMPUTE
}

// ---------------- RoPE on Q,K: one sincos per (row, freq), 16 heads ----------------
__global__ __launch_bounds__(256) void rope_kernel(u16* __restrict__ Qb, u16* __restrict__ Kb,
                                                   const int* __restrict__ pos){
  const int t = blockIdx.x*256 + threadIdx.x;   // 0..131071
  const int m = t >> 5;                         // row 0..4095
  const int fi = t & 31;                        // freq index
  const float invf = __expf(-(float)fi * 0.28782313662425575f);  // ln(10000)/32
  float s, c;
  sincosf((float)pos[m] * invf, &s, &c);
  const size_t base = (size_t)m*DM + fi*2;
  #pragma unroll
  for (int h=0; h<NH; h++){
    const size_t a = base + h*HD;
    {
      const float x0 = b2f(Qb[a]), x1 = b2f(Qb[a+1]);
      Qb[a]   = f2b(c*x0 - s*x1);
      Qb[a+1] = f2b(c*x1 + s*x0);
    }
    {
      const float x0 = b2f(Kb[a]), x1 = b2f(Kb[a+1]);
      Kb[a]   = f2b(c*x0 - s*x1);
      Kb[a+1] = f2b(c*x1 + s*x0);
    }
  }
}

// ---------------- V transpose: Vb[b*T+s][h*64+d] -> Vt[bh][d][s] ----------------
__global__ __launch_bounds__(256) void transpose_v_kernel(const u16* __restrict__ Vb,
                                                          u16* __restrict__ Vt){
  __shared__ u16 tile[64][72];
  const int bh = blockIdx.x >> 5;
  const int sc = blockIdx.x & 31;
  const int bq = bh >> 4, h = bh & 15;
  const int s0 = sc*64;
  {
    const int row = threadIdx.x >> 3;
    const int c8 = (threadIdx.x & 7)*8;
    #pragma unroll
    for (int rr = 0; rr < 64; rr += 32){
      const short8 v = *(const short8*)(Vb + (size_t)(bq*TT + s0 + row + rr)*DM + h*HD + c8);
      *(short8*)(&tile[row+rr][c8]) = v;
    }
  }
  __syncthreads();
  {
    const int d = threadIdx.x >> 3;
    const int s8 = (threadIdx.x & 7)*8;
    #pragma unroll
    for (int dd = 0; dd < 64; dd += 32){
      short8 ov;
      #pragma unroll
      for (int j=0;j<8;j++) ov[j] = (short)tile[s8+j][d+dd];
      *(short8*)(Vt + ((size_t)bh*HD + d + dd)*TT + s0 + s8) = ov;
    }
  }
}

// ---------------- causal flash attention (paired q-tiles) ----------------
__device__ __forceinline__ void proc_tile(
    const short8 qf0, const short8 qf1,
    const short8 k00, const short8 k01, const short8 k10, const short8 k11,
    const short8 v0, const short8 v1, const short8 v2, const short8 v3,
    f32x4& o0, f32x4& o1, f32x4& o2, f32x4& o3,
    float (&mrow)[4], float (&lrow)[4],
    const int q0, const int s0, const int r, const int g,
    u16 (*pbuf)[40]){
  f32x4 sa0={0,0,0,0}, sa1={0,0,0,0};
  sa0 = __builtin_amdgcn_mfma_f32_16x16x32_bf16(qf0, k00, sa0, 0,0,0);
  sa0 = __builtin_amdgcn_mfma_f32_16x16x32_bf16(qf1, k01, sa0, 0,0,0);
  sa1 = __builtin_amdgcn_mfma_f32_16x16x32_bf16(qf0, k10, sa1, 0,0,0);
  sa1 = __builtin_amdgcn_mfma_f32_16x16x32_bf16(qf1, k11, sa1, 0,0,0);

  float sv0[4], sv1[4], pm[4];
  #pragma unroll
  for (int i=0;i<4;i++){
    const int q = q0 + g*4 + i;
    sv0[i] = (s0 + r      <= q) ? sa0[i]*0.125f : -3.0e38f;
    sv1[i] = (s0 + 16 + r <= q) ? sa1[i]*0.125f : -3.0e38f;
    pm[i] = fmaxf(sv0[i], sv1[i]);
  }
  #pragma unroll
  for (int off=8; off>0; off>>=1){
    #pragma unroll
    for (int i=0;i<4;i++) pm[i] = fmaxf(pm[i], __shfl_xor(pm[i], off));
  }
  float corr[4], p0[4], p1[4], ps[4];
  #pragma unroll
  for (int i=0;i<4;i++){
    const float mn = fmaxf(mrow[i], pm[i]);
    corr[i] = __expf(mrow[i] - mn);
    mrow[i] = mn;
    p0[i] = __expf(sv0[i] - mn);
    p1[i] = __expf(sv1[i] - mn);
    ps[i] = p0[i] + p1[i];
  }
  #pragma unroll
  for (int off=8; off>0; off>>=1){
    #pragma unroll
    for (int i=0;i<4;i++) ps[i] += __shfl_xor(ps[i], off);
  }
  #pragma unroll
  for (int i=0;i<4;i++){
    lrow[i] = lrow[i]*corr[i] + ps[i];
    o0[i] *= corr[i]; o1[i] *= corr[i]; o2[i] *= corr[i]; o3[i] *= corr[i];
    pbuf[g*4+i][r]      = f2b(p0[i]);
    pbuf[g*4+i][16 + r] = f2b(p1[i]);
  }
  const short8 pf = *(const short8*)(&pbuf[r][g*8]);
  o0 = __builtin_amdgcn_mfma_f32_16x16x32_bf16(pf, v0, o0, 0,0,0);
  o1 = __builtin_amdgcn_mfma_f32_16x16x32_bf16(pf, v1, o1, 0,0,0);
  o2 = __builtin_amdgcn_mfma_f32_16x16x32_bf16(pf, v2, o2, 0,0,0);
  o3 = __builtin_amdgcn_mfma_f32_16x16x32_bf16(pf, v3, o3, 0,0,0);
}

__global__ __launch_bounds__(256) void attn_kernel(const u16* __restrict__ Qb,
                                                   const u16* __restrict__ Kb,
                                                   const u16* __restrict__ Vt,
                                                   u16* __restrict__ Ob){
  __shared__ u16 Plds[4][2][16][40];
  const int lane = threadIdx.x & 63;
  const int wave = threadIdx.x >> 6;
  const int wg = blockIdx.x*4 + wave;   // 0..2047
  const int qt = wg & 63;               // pair id
  const int bh = wg >> 6;               // 0..31
  const int bq = bh >> 4;
  const int h = bh & 15;
  const int qlo = qt << 4;
  const int qhi = (127 - qt) << 4;
  const int r = lane & 15, g = lane >> 4;

  const u16* QrowL = Qb + (size_t)(bq*TT + qlo + r)*DM + h*HD;
  const u16* QrowH = Qb + (size_t)(bq*TT + qhi + r)*DM + h*HD;
  const short8 qL0 = *(const short8*)(QrowL + g*8);
  const short8 qL1 = *(const short8*)(QrowL + 32 + g*8);
  const short8 qH0 = *(const short8*)(QrowH + g*8);
  const short8 qH1 = *(const short8*)(QrowH + 32 + g*8);

  f32x4 oL0={0,0,0,0}, oL1={0,0,0,0}, oL2={0,0,0,0}, oL3={0,0,0,0};
  f32x4 oH0={0,0,0,0}, oH1={0,0,0,0}, oH2={0,0,0,0}, oH3={0,0,0,0};
  float mL[4], lL[4], mH[4], lH[4];
  #pragma unroll
  for (int i=0;i<4;i++){ mL[i]=-3.0e38f; lL[i]=0.f; mH[i]=-3.0e38f; lH[i]=0.f; }

  const int nbL = ((qlo + 15) >> 5) + 1;
  const int nbH = ((qhi + 15) >> 5) + 1;
  const u16* Kbase = Kb + (size_t)(bq*TT)*DM + h*HD;
  const u16* Vtb = Vt + (size_t)bh*HD*TT;

  for (int ib = 0; ib < nbH; ib++){
    const int s0 = ib << 5;
    const u16* Kr0 = Kbase + (size_t)(s0 + r)*DM;
    const u16* Kr1 = Kr0 + (size_t)16*DM;
    const short8 k00 = *(const short8*)(Kr0 + g*8);
    const short8 k01 = *(const short8*)(Kr0 + 32 + g*8);
    const short8 k10 = *(const short8*)(Kr1 + g*8);
    const short8 k11 = *(const short8*)(Kr1 + 32 + g*8);
    const u16* Vr = Vtb + (size_t)r*TT + s0 + g*8;
    const short8 v0 = *(const short8*)(Vr);
    const short8 v1 = *(const short8*)(Vr + (size_t)16*TT);
    const short8 v2 = *(const short8*)(Vr + (size_t)32*TT);
    const short8 v3 = *(const short8*)(Vr + (size_t)48*TT);

    proc_tile(qH0,qH1,k00,k01,k10,k11,v0,v1,v2,v3,
              oH0,oH1,oH2,oH3,mH,lH,qhi,s0,r,g,Plds[wave][0]);
    if (ib < nbL){
      proc_tile(qL0,qL1,k00,k01,k10,k11,v0,v1,v2,v3,
                oL0,oL1,oL2,oL3,mL,lL,qlo,s0,r,g,Plds[wave][1]);
    }
  }
  float invL[4], invH[4];
  #pragma unroll
  for (int i=0;i<4;i++){ invL[i] = 1.0f/lL[i]; invH[i] = 1.0f/lH[i]; }
  #pragma unroll
  for (int i=0;i<4;i++){
    const size_t rowL = (size_t)(bq*TT + qlo + g*4 + i)*DM + h*HD;
    Ob[rowL + r]      = f2b(oL0[i]*invL[i]);
    Ob[rowL + 16 + r] = f2b(oL1[i]*invL[i]);
    Ob[rowL + 32 + r] = f2b(oL2[i]*invL[i]);
    Ob[rowL + 48 + r] = f2b(oL3[i]*invL[i]);
    const size_t rowH = (size_t)(bq*TT + qhi + g*4 + i)*DM + h*HD;
    Ob[rowH + r]      = f2b(oH0[i]*invH[i]);
    Ob[rowH + 16 + r] = f2b(oH1[i]*invH[i]);
    Ob[rowH + 32 + r] = f2b(oH2[i]*invH[i]);
    Ob[rowH + 48 + r] = f2b(oH3[i]*invH[i]);
  }
}

extern "C" void kernel_launch(void* const* d_in, const int* in_sizes, int n_in,
                              void* d_out, int out_size, void* d_ws, size_t ws_size,
                              hipStream_t stream) {
  const float* X  = (const float*)d_in[0];
  const int* pos  = (const int*)d_in[1];
  const float* Wq = (const float*)d_in[2];
  const float* Wk = (const float*)d_in[3];
  const float* Wv = (const float*)d_in[4];
  const float* Wo = (const float*)d_in[5];
  float* out = (float*)d_out;

  char* ws = (char*)d_ws;
  u16* Xb = (u16*)ws;                                    // 8 MB (reused as Vt later)
  u16* Vt = (u16*)ws;                                    // aliases Xb (dead after QKV gemm)
  u16* Wb = (u16*)(ws + (size_t)8*1024*1024);            // 4 x 2 MB (q,k,v,o)
  u16* Qb = (u16*)(ws + (size_t)16*1024*1024);           // 8 MB
  u16* Kb = Qb + (size_t)BT*DM;                          // 8 MB
  u16* Vb = Kb + (size_t)BT*DM;                          // 8 MB
  u16* Ob = (u16*)(ws + (size_t)40*1024*1024);           // 8 MB

  const int DD = DM*DM;
  cvt_kernel<<<4096, 256, 0, stream>>>(X, Xb, BT*DM/4);
  cvt_w_kernel<<<4096, 256, 0, stream>>>(Wq, Wk, Wv, Wo, Wb);

  gemm128<0><<<dim3(24, 32), 256, 0, stream>>>(Xb, Wb, Qb, nullptr);
  rope_kernel<<<512, 256, 0, stream>>>(Qb, Kb, pos);
  transpose_v_kernel<<<1024, 256, 0, stream>>>(Vb, Vt);
  attn_kernel<<<512, 256, 0, stream>>>(Qb, Kb, Vt, Ob);
  gemm128<1><<<dim3(8, 32), 256, 0, stream>>>(Ob, Wb + 3*DD, nullptr, out);
}